// Round 5
// baseline (2460.280 us; speedup 1.0000x reference)
//
#include <hip/hip_runtime.h>

#define NTOK 49
#define DIM 384
#define HEADS 12
#define SCALE 0.17677669529663687f

typedef __attribute__((ext_vector_type(8))) short bf16x8;
typedef __attribute__((ext_vector_type(4))) float f32x4;

#define MFMA16(a, b, c) __builtin_amdgcn_mfma_f32_16x16x32_bf16((a), (b), (c), 0, 0, 0)

__device__ __forceinline__ short f2bf(float f) {
  union { float f; unsigned u; } v; v.f = f;
  unsigned r = (v.u + 0x7FFFu + ((v.u >> 16) & 1u)) >> 16;
  return (short)(unsigned short)r;
}

// Zero-padded "K=16" fragment for 16x16x32 MFMA: elements 0..3 = data, 4..7 = 0.
// Exact: A and B use the same k-relabel (k32 = 8g+j <-> k16 = 4g+j), pad terms
// multiply 0 on at least one side.
__device__ __forceinline__ bf16x8 pack4(float a, float b, float c, float d) {
  bf16x8 r = {0, 0, 0, 0, 0, 0, 0, 0};
  r[0] = f2bf(a); r[1] = f2bf(b); r[2] = f2bf(c); r[3] = f2bf(d);
  return r;
}

// ws layout:
//   wqT  : short [384][384]          elem off 0        (Wq^T row-major: [n][k])
//   wkvT : short [768][384]          elem off 147456   (rows 0-383 K, 384-767 V)
//   wpT  : short [384][384]          elem off 442368
//   biasq: float [12][49][52]        byte off 1179648  ([h][q][k], k padded 49->52)
#define WQT_OFF   0
#define WKVT_OFF  147456
#define WPT_OFF   442368
#define BIAS_BYTE_OFF 1179648
#define BIAS_RL   52

__global__ void prep_kernel(const float* __restrict__ qw, const float* __restrict__ kvw,
                            const float* __restrict__ pw, const float* __restrict__ bt,
                            short* __restrict__ wsS, float* __restrict__ biasq) {
  int id = blockIdx.x * 256 + threadIdx.x;
  const int SZ1 = 384 * 384;
  const int SZ2 = 768 * 384;
  const int SZ3 = 384 * 384;
  if (id < SZ1) {
    int n = id / 384, k = id % 384;
    wsS[WQT_OFF + id] = f2bf(qw[k * 384 + n]);
  } else if (id < SZ1 + SZ2) {
    int t = id - SZ1; int n = t / 384, k = t % 384;
    wsS[WKVT_OFF + t] = f2bf(kvw[k * 768 + n]);
  } else if (id < SZ1 + SZ2 + SZ3) {
    int t = id - (SZ1 + SZ2); int n = t / 384, k = t % 384;
    wsS[WPT_OFF + t] = f2bf(pw[k * 384 + n]);
  } else if (id < SZ1 + SZ2 + SZ3 + HEADS * NTOK * BIAS_RL) {
    int t = id - (SZ1 + SZ2 + SZ3);
    int h = t / (NTOK * BIAS_RL); int rc = t % (NTOK * BIAS_RL);
    int q = rc / BIAS_RL, c = rc % BIAS_RL;
    float v = 0.0f;
    if (c < NTOK) {
      int idx = ((q / 7 - c / 7) + 6) * 13 + ((q % 7 - c % 7) + 6);
      v = bt[idx * HEADS + h];
    }
    biasq[t] = v;
  }
}

// LDS (shorts). Row stride 392 -> 784B = 196 dw == 4 mod 32: 16-lane b128 frag
// reads spread over banks at <=2-way aliasing (free).
#define X_OFF    0            // [49][392]  x_body
#define XE_OFF   19208        // [49][392]  x_edge; reused as OALL after Q phase
#define LDS_ELEMS 38416
#define LDS_BYTES (LDS_ELEMS * 2)   // 76832 -> 2 blocks/CU, 24 waves/CU

__global__ __launch_bounds__(768, 6)
void fused_kernel(const float* __restrict__ xe, const float* __restrict__ xb,
                  const float* __restrict__ qb, const float* __restrict__ kvb,
                  const float* __restrict__ pb,
                  const short* __restrict__ wqT, const short* __restrict__ wkvT,
                  const short* __restrict__ wpT, const float* __restrict__ biasq,
                  float* __restrict__ out) {
  extern __shared__ short lds[];
  short* X    = lds + X_OFF;     // x_body
  short* XE   = lds + XE_OFF;    // x_edge
  short* OALL = XE;              // O tiles after Q phase (XE dead)

  const int b   = blockIdx.x;
  const int tid = threadIdx.x;
  const int w   = tid >> 6;      // 0..11 = head
  const int l   = tid & 63;
  const int m16 = l & 15;
  const int g   = l >> 4;
  const int h   = w;

  const f32x4 zf = {0.f, 0.f, 0.f, 0.f};

  // ---- stage x_edge -> XE and x_body -> X (bf16, 8B packed writes) ----
  const float* xew = xe + (size_t)b * (NTOK * DIM);
  const float* xbw = xb + (size_t)b * (NTOK * DIM);
  for (int i4 = tid; i4 < 2 * (NTOK * DIM / 4); i4 += 768) {
    int eb = i4 < (NTOK * DIM / 4);
    int e = (eb ? i4 : i4 - NTOK * DIM / 4) * 4;
    const float* src = eb ? xew : xbw;
    short* dst = eb ? XE : X;
    int r = e / DIM, c = e % DIM;
    float4 v = *(const float4*)(src + e);
    ushort4 s;
    s.x = (unsigned short)f2bf(v.x); s.y = (unsigned short)f2bf(v.y);
    s.z = (unsigned short)f2bf(v.z); s.w = (unsigned short)f2bf(v.w);
    *(ushort4*)&dst[r * 392 + c] = s;
  }
  __syncthreads();   // [#1]

  // ================= Q^T GEMM (wave-private): C[d][tok] =================
  f32x4 qc[2][4];
#pragma unroll
  for (int dt = 0; dt < 2; ++dt)
#pragma unroll
    for (int tb = 0; tb < 4; ++tb) qc[dt][tb] = zf;
#pragma unroll
  for (int kk = 0; kk < 12; ++kk) {
    const int ko = kk * 32 + g * 8;
    bf16x8 xv[4];
#pragma unroll
    for (int tb = 0; tb < 4; ++tb) {
      int tr = tb * 16 + m16; tr = tr < 49 ? tr : 48;
      xv[tb] = *(const bf16x8*)(&XE[tr * 392 + ko]);
    }
#pragma unroll
    for (int dt = 0; dt < 2; ++dt) {
      bf16x8 aw = *(const bf16x8*)(wqT + (size_t)(h * 32 + dt * 16 + m16) * 384 + ko);
#pragma unroll
      for (int tb = 0; tb < 4; ++tb) qc[dt][tb] = MFMA16(aw, xv[tb], qc[dt][tb]);
    }
  }
  // convert to zero-padded frags (bias + scale folded); lane m16 = q
  bf16x8 qfr[2][4];
#pragma unroll
  for (int dt = 0; dt < 2; ++dt) {
    float b0 = qb[h * 32 + dt * 16 + g * 4 + 0];
    float b1 = qb[h * 32 + dt * 16 + g * 4 + 1];
    float b2 = qb[h * 32 + dt * 16 + g * 4 + 2];
    float b3 = qb[h * 32 + dt * 16 + g * 4 + 3];
#pragma unroll
    for (int tb = 0; tb < 4; ++tb)
      qfr[dt][tb] = pack4((qc[dt][tb][0] + b0) * SCALE, (qc[dt][tb][1] + b1) * SCALE,
                          (qc[dt][tb][2] + b2) * SCALE, (qc[dt][tb][3] + b3) * SCALE);
  }
  __syncthreads();   // [#2] all XE reads done -> XE becomes OALL

  // ================= K^T + V GEMM (wave-private, shared X frags) =========
  f32x4 kc[2][4], vc[4][2];
#pragma unroll
  for (int dt = 0; dt < 2; ++dt)
#pragma unroll
    for (int tb = 0; tb < 4; ++tb) kc[dt][tb] = zf;
#pragma unroll
  for (int tb = 0; tb < 4; ++tb)
#pragma unroll
    for (int db = 0; db < 2; ++db) vc[tb][db] = zf;

#pragma unroll
  for (int kk = 0; kk < 12; ++kk) {
    const int ko = kk * 32 + g * 8;
    bf16x8 xv[4];
#pragma unroll
    for (int tb = 0; tb < 4; ++tb) {
      int tr = tb * 16 + m16; tr = tr < 49 ? tr : 48;
      xv[tb] = *(const bf16x8*)(&X[tr * 392 + ko]);
    }
    bf16x8 kw[2], vw[2];
#pragma unroll
    for (int dt = 0; dt < 2; ++dt)
      kw[dt] = *(const bf16x8*)(wkvT + (size_t)(h * 32 + dt * 16 + m16) * 384 + ko);
#pragma unroll
    for (int db = 0; db < 2; ++db)
      vw[db] = *(const bf16x8*)(wkvT + (size_t)(384 + h * 32 + db * 16 + m16) * 384 + ko);
#pragma unroll
    for (int dt = 0; dt < 2; ++dt)
#pragma unroll
      for (int tb = 0; tb < 4; ++tb) kc[dt][tb] = MFMA16(kw[dt], xv[tb], kc[dt][tb]);
#pragma unroll
    for (int tb = 0; tb < 4; ++tb)
#pragma unroll
      for (int db = 0; db < 2; ++db) vc[tb][db] = MFMA16(xv[tb], vw[db], vc[tb][db]);
  }
  bf16x8 kfr[2][4], vfr[4][2];
#pragma unroll
  for (int dt = 0; dt < 2; ++dt) {
    float b0 = kvb[h * 32 + dt * 16 + g * 4 + 0];
    float b1 = kvb[h * 32 + dt * 16 + g * 4 + 1];
    float b2 = kvb[h * 32 + dt * 16 + g * 4 + 2];
    float b3 = kvb[h * 32 + dt * 16 + g * 4 + 3];
#pragma unroll
    for (int tb = 0; tb < 4; ++tb)
      kfr[dt][tb] = pack4(kc[dt][tb][0] + b0, kc[dt][tb][1] + b1,
                          kc[dt][tb][2] + b2, kc[dt][tb][3] + b3);
  }
#pragma unroll
  for (int db = 0; db < 2; ++db) {
    float vbv = kvb[384 + h * 32 + db * 16 + m16];
#pragma unroll
    for (int tb = 0; tb < 4; ++tb)
      vfr[tb][db] = pack4(vc[tb][db][0] + vbv, vc[tb][db][1] + vbv,
                          vc[tb][db][2] + vbv, vc[tb][db][3] + vbv);
  }

  // ================= S^T = K Q^T (in-register) =================
  // s[tb][qb]: lane holds S[q = qb*16+m16][k = tb*16+g*4+i]
  f32x4 s[4][4];
#pragma unroll
  for (int tb = 0; tb < 4; ++tb)
#pragma unroll
    for (int qb = 0; qb < 4; ++qb) {
      f32x4 t = MFMA16(kfr[0][tb], qfr[0][qb], zf);
      s[tb][qb] = MFMA16(kfr[1][tb], qfr[1][qb], t);
    }

  // ================= softmax + PV per q-tile, O -> OALL =================
#pragma unroll
  for (int qb = 0; qb < 4; ++qb) {
    int q = qb * 16 + m16; int qcl = q < 49 ? q : 48;
    const float* bq = biasq + (size_t)(h * NTOK + qcl) * BIAS_RL;
    float sv[4][4];
    float mx = -3.0e38f;
#pragma unroll
    for (int tb = 0; tb < 4; ++tb) {
      int k0 = tb * 16 + g * 4;
      int kcl = k0 <= 48 ? k0 : 48;
      float4 bv = *(const float4*)(bq + kcl);
      float x0 = s[tb][qb][0] + bv.x, x1 = s[tb][qb][1] + bv.y;
      float x2 = s[tb][qb][2] + bv.z, x3 = s[tb][qb][3] + bv.w;
      sv[tb][0] = (k0 + 0 < 49) ? x0 : -3.0e38f;
      sv[tb][1] = (k0 + 1 < 49) ? x1 : -3.0e38f;
      sv[tb][2] = (k0 + 2 < 49) ? x2 : -3.0e38f;
      sv[tb][3] = (k0 + 3 < 49) ? x3 : -3.0e38f;
      mx = fmaxf(mx, fmaxf(fmaxf(sv[tb][0], sv[tb][1]), fmaxf(sv[tb][2], sv[tb][3])));
    }
    mx = fmaxf(mx, __shfl_xor(mx, 16));
    mx = fmaxf(mx, __shfl_xor(mx, 32));
    float sum = 0.f;
#pragma unroll
    for (int tb = 0; tb < 4; ++tb)
#pragma unroll
      for (int i = 0; i < 4; ++i) {
        float e = __expf(sv[tb][i] - mx);
        sv[tb][i] = e;
        sum += e;
      }
    sum += __shfl_xor(sum, 16);
    sum += __shfl_xor(sum, 32);
    float inv = 1.0f / sum;
    bf16x8 pfr[4];
#pragma unroll
    for (int tb = 0; tb < 4; ++tb)
      pfr[tb] = pack4(sv[tb][0] * inv, sv[tb][1] * inv, sv[tb][2] * inv, sv[tb][3] * inv);
    f32x4 o0 = zf, o1 = zf;
#pragma unroll
    for (int kt = 0; kt < 4; ++kt) {
      o0 = MFMA16(pfr[kt], vfr[kt][0], o0);
      o1 = MFMA16(pfr[kt], vfr[kt][1], o1);
    }
#pragma unroll
    for (int i = 0; i < 4; ++i) {
      int r = qb * 16 + g * 4 + i;
      if (r < 49) {
        OALL[r * 392 + h * 32 + m16]      = f2bf(o0[i]);
        OALL[r * 392 + h * 32 + 16 + m16] = f2bf(o1[i]);
      }
    }
  }
  __syncthreads();   // [#3] OALL complete

  // ================= out-projection: wave owns 2 col-tiles =================
  f32x4 pacc[4][2];
#pragma unroll
  for (int qt = 0; qt < 4; ++qt)
#pragma unroll
    for (int ct = 0; ct < 2; ++ct) pacc[qt][ct] = zf;
#pragma unroll
  for (int kk = 0; kk < 12; ++kk) {
    const int ko = kk * 32 + g * 8;
    bf16x8 af[4];
#pragma unroll
    for (int qt = 0; qt < 4; ++qt) {
      int r = qt * 16 + m16; r = r < 49 ? r : 48;
      af[qt] = *(const bf16x8*)(&OALL[r * 392 + ko]);
    }
#pragma unroll
    for (int ct = 0; ct < 2; ++ct) {
      bf16x8 bw = *(const bf16x8*)(wpT + (size_t)((w * 2 + ct) * 16 + m16) * 384 + ko);
#pragma unroll
      for (int qt = 0; qt < 4; ++qt) pacc[qt][ct] = MFMA16(af[qt], bw, pacc[qt][ct]);
    }
  }
  float* outw = out + (size_t)b * (NTOK * DIM);
#pragma unroll
  for (int ct = 0; ct < 2; ++ct) {
    int col = (w * 2 + ct) * 16 + m16;
    float pbv = pb[col];
#pragma unroll
    for (int qt = 0; qt < 4; ++qt)
#pragma unroll
      for (int i = 0; i < 4; ++i) {
        int r = qt * 16 + g * 4 + i;
        if (r < 49) outw[r * DIM + col] = pacc[qt][ct][i] + pbv;
      }
  }
}

extern "C" void kernel_launch(void* const* d_in, const int* in_sizes, int n_in,
                              void* d_out, int out_size, void* d_ws, size_t ws_size,
                              hipStream_t stream) {
  const float* xe  = (const float*)d_in[0];
  const float* xb  = (const float*)d_in[1];
  const float* qw  = (const float*)d_in[2];
  const float* qb  = (const float*)d_in[3];
  const float* kvw = (const float*)d_in[4];
  const float* kvb = (const float*)d_in[5];
  const float* pw  = (const float*)d_in[6];
  const float* pb  = (const float*)d_in[7];
  const float* bt  = (const float*)d_in[8];
  float* out = (float*)d_out;
  short* wsS = (short*)d_ws;
  float* biasq = (float*)((char*)d_ws + BIAS_BYTE_OFF);

  const int nwin = in_sizes[0] / (NTOK * DIM);

  const int prep_items = 384 * 384 + 768 * 384 + 384 * 384 + HEADS * NTOK * BIAS_RL;
  prep_kernel<<<(prep_items + 255) / 256, 256, 0, stream>>>(qw, kvw, pw, bt, wsS, biasq);

  hipFuncSetAttribute((const void*)fused_kernel,
                      hipFuncAttributeMaxDynamicSharedMemorySize, LDS_BYTES);
  fused_kernel<<<nwin, 768, LDS_BYTES, stream>>>(
      xe, xb, qb, kvb, pb,
      wsS + WQT_OFF, wsS + WKVT_OFF, wsS + WPT_OFF, biasq, out);
}

// Round 6
// 1088.440 us; speedup vs baseline: 2.2604x; 2.2604x over previous
//
#include <hip/hip_runtime.h>
#include <hip/hip_bf16.h>

#define NTOK 49
#define DIM 384
#define HEADS 12
#define SCALE 0.17677669529663687f

typedef __attribute__((ext_vector_type(8))) short bf16x8;
typedef __attribute__((ext_vector_type(4))) float f32x4;

#define MFMA16(a, b, c) __builtin_amdgcn_mfma_f32_16x16x32_bf16((a), (b), (c), 0, 0, 0)

__device__ __forceinline__ short f2bf(float f) {
  __hip_bfloat16 h = __float2bfloat16(f);
  return __builtin_bit_cast(short, h);
}

// Full-K=32 fragment from two K=16 C-tile slices: element j<4 = slice0 value at
// d16 = 4g+j, j>=4 = slice1 at d16 = 4g+(j-4). Exact when A and B frags use the
// same relabel (each of the 32 k-indices appears exactly once on both sides).
__device__ __forceinline__ bf16x8 pack8(f32x4 a, f32x4 b) {
  bf16x8 r;
#pragma unroll
  for (int i = 0; i < 4; ++i) { r[i] = f2bf(a[i]); r[i + 4] = f2bf(b[i]); }
  return r;
}

// ws layout:
//   wqT  : short [384][384]          elem off 0        (Wq^T row-major: [n][k])
//   wkvT : short [768][384]          elem off 147456   (rows 0-383 K, 384-767 V)
//   wpT  : short [384][384]          elem off 442368
//   biasq: float [12][49][52]        byte off 1179648  ([h][q][k], k padded 49->52)
#define WQT_OFF   0
#define WKVT_OFF  147456
#define WPT_OFF   442368
#define BIAS_BYTE_OFF 1179648
#define BIAS_RL   52

__global__ void prep_kernel(const float* __restrict__ qw, const float* __restrict__ kvw,
                            const float* __restrict__ pw, const float* __restrict__ bt,
                            short* __restrict__ wsS, float* __restrict__ biasq) {
  int id = blockIdx.x * 256 + threadIdx.x;
  const int SZ1 = 384 * 384;
  const int SZ2 = 768 * 384;
  const int SZ3 = 384 * 384;
  if (id < SZ1) {
    int n = id / 384, k = id % 384;
    wsS[WQT_OFF + id] = f2bf(qw[k * 384 + n]);
  } else if (id < SZ1 + SZ2) {
    int t = id - SZ1; int n = t / 384, k = t % 384;
    wsS[WKVT_OFF + t] = f2bf(kvw[k * 768 + n]);
  } else if (id < SZ1 + SZ2 + SZ3) {
    int t = id - (SZ1 + SZ2); int n = t / 384, k = t % 384;
    wsS[WPT_OFF + t] = f2bf(pw[k * 384 + n]);
  } else if (id < SZ1 + SZ2 + SZ3 + HEADS * NTOK * BIAS_RL) {
    int t = id - (SZ1 + SZ2 + SZ3);
    int h = t / (NTOK * BIAS_RL); int rc = t % (NTOK * BIAS_RL);
    int q = rc / BIAS_RL, c = rc % BIAS_RL;
    float v = 0.0f;
    if (c < NTOK) {
      int idx = ((q / 7 - c / 7) + 6) * 13 + ((q % 7 - c % 7) + 6);
      v = bt[idx * HEADS + h];
    }
    biasq[t] = v;
  }
}

// LDS (shorts). Row stride 392 -> 784B = 196 dw == 4 mod 32: 16-row b128 frag
// reads land 2 lanes/bank (free).
#define X_OFF    0            // [49][392]  x_body
#define XE_OFF   19208        // [49][392]  x_edge; reused as OALL after Q phase
#define LDS_ELEMS 38416
#define LDS_BYTES (LDS_ELEMS * 2)   // 76832 B -> 2 blocks/CU

__global__ __launch_bounds__(384, 3)
void fused_kernel(const float* __restrict__ xe, const float* __restrict__ xb,
                  const float* __restrict__ qb, const float* __restrict__ kvb,
                  const float* __restrict__ pb,
                  const short* __restrict__ wqT, const short* __restrict__ wkvT,
                  const short* __restrict__ wpT, const float* __restrict__ biasq,
                  float* __restrict__ out) {
  extern __shared__ short lds[];
  short* X    = lds + X_OFF;     // x_body
  short* XE   = lds + XE_OFF;    // x_edge
  short* OALL = XE;              // O tiles after Q phase (XE dead)

  const int b   = blockIdx.x;
  const int tid = threadIdx.x;
  const int u   = tid >> 6;      // wave 0..5, owns heads 2u, 2u+1
  const int l   = tid & 63;
  const int m16 = l & 15;
  const int g   = l >> 4;

  const f32x4 zf = {0.f, 0.f, 0.f, 0.f};

  // ---- stage x_edge -> XE and x_body -> X (bf16, 8B packed writes) ----
  const float* xew = xe + (size_t)b * (NTOK * DIM);
  const float* xbw = xb + (size_t)b * (NTOK * DIM);
  for (int i4 = tid; i4 < 2 * (NTOK * DIM / 4); i4 += 384) {
    int eb = i4 < (NTOK * DIM / 4);
    int e = (eb ? i4 : i4 - NTOK * DIM / 4) * 4;
    const float* src = eb ? xew : xbw;
    short* dst = eb ? XE : X;
    int r = e / DIM, c = e % DIM;
    float4 v = *(const float4*)(src + e);
    ushort4 s;
    s.x = (unsigned short)f2bf(v.x); s.y = (unsigned short)f2bf(v.y);
    s.z = (unsigned short)f2bf(v.z); s.w = (unsigned short)f2bf(v.w);
    *(ushort4*)&dst[r * 392 + c] = s;
  }
  __syncthreads();   // [#1]

  // ================= Q^T GEMM for heads 2u, 2u+1 (wave-private) ============
  // qc[hh][dt][tb]: C[d_local = g*4+i][tok = tb*16+m16]
  f32x4 qc[2][2][4];
#pragma unroll
  for (int hh = 0; hh < 2; ++hh)
#pragma unroll
    for (int dt = 0; dt < 2; ++dt)
#pragma unroll
      for (int tb = 0; tb < 4; ++tb) qc[hh][dt][tb] = zf;

#pragma unroll
  for (int kk = 0; kk < 12; ++kk) {
    const int ko = kk * 32 + g * 8;
    bf16x8 xv[4];
#pragma unroll
    for (int tb = 0; tb < 4; ++tb) {
      int tr = tb * 16 + m16; tr = tr < 49 ? tr : 48;
      xv[tb] = *(const bf16x8*)(&XE[tr * 392 + ko]);
    }
#pragma unroll
    for (int hh = 0; hh < 2; ++hh)
#pragma unroll
      for (int dt = 0; dt < 2; ++dt) {
        bf16x8 aw = *(const bf16x8*)(wqT + (size_t)((2 * u + hh) * 32 + dt * 16 + m16) * 384 + ko);
#pragma unroll
        for (int tb = 0; tb < 4; ++tb) qc[hh][dt][tb] = MFMA16(aw, xv[tb], qc[hh][dt][tb]);
      }
  }
  // fold bias+scale, merge dt slices into full-K frags; lane m16 = q
  bf16x8 qfr[2][4];
#pragma unroll
  for (int hh = 0; hh < 2; ++hh) {
    const int h = 2 * u + hh;
    float4 t0 = *(const float4*)(qb + h * 32 + g * 4);
    float4 t1 = *(const float4*)(qb + h * 32 + 16 + g * 4);
    f32x4 b0 = {t0.x, t0.y, t0.z, t0.w};
    f32x4 b1 = {t1.x, t1.y, t1.z, t1.w};
#pragma unroll
    for (int qt = 0; qt < 4; ++qt)
      qfr[hh][qt] = pack8((qc[hh][0][qt] + b0) * SCALE, (qc[hh][1][qt] + b1) * SCALE);
  }
  __syncthreads();   // [#2] all XE reads done -> XE becomes OALL

  // ================= per head: K,V GEMM + attention (no barriers) ==========
#pragma unroll
  for (int hh = 0; hh < 2; ++hh) {
    const int h = 2 * u + hh;
    f32x4 kc[2][4], vc[4][2];
#pragma unroll
    for (int dt = 0; dt < 2; ++dt)
#pragma unroll
      for (int tb = 0; tb < 4; ++tb) kc[dt][tb] = zf;
#pragma unroll
    for (int tb = 0; tb < 4; ++tb)
#pragma unroll
      for (int db = 0; db < 2; ++db) vc[tb][db] = zf;

#pragma unroll
    for (int kk = 0; kk < 12; ++kk) {
      const int ko = kk * 32 + g * 8;
      bf16x8 xv[4];
#pragma unroll
      for (int tb = 0; tb < 4; ++tb) {
        int tr = tb * 16 + m16; tr = tr < 49 ? tr : 48;
        xv[tb] = *(const bf16x8*)(&X[tr * 392 + ko]);
      }
      bf16x8 kw[2], vw[2];
#pragma unroll
      for (int dt = 0; dt < 2; ++dt)
        kw[dt] = *(const bf16x8*)(wkvT + (size_t)(h * 32 + dt * 16 + m16) * 384 + ko);
#pragma unroll
      for (int db = 0; db < 2; ++db)
        vw[db] = *(const bf16x8*)(wkvT + (size_t)(384 + h * 32 + db * 16 + m16) * 384 + ko);
#pragma unroll
      for (int dt = 0; dt < 2; ++dt)
#pragma unroll
        for (int tb = 0; tb < 4; ++tb) kc[dt][tb] = MFMA16(kw[dt], xv[tb], kc[dt][tb]);
#pragma unroll
      for (int tb = 0; tb < 4; ++tb)
#pragma unroll
        for (int db = 0; db < 2; ++db) vc[tb][db] = MFMA16(xv[tb], vw[db], vc[tb][db]);
    }
    // K frags: lane m16 = ktok; V frags: lane m16 = vd
    bf16x8 kfr[4], vfr[2][2];
    {
      float4 t0 = *(const float4*)(kvb + h * 32 + g * 4);
      float4 t1 = *(const float4*)(kvb + h * 32 + 16 + g * 4);
      f32x4 b0 = {t0.x, t0.y, t0.z, t0.w};
      f32x4 b1 = {t1.x, t1.y, t1.z, t1.w};
#pragma unroll
      for (int tb = 0; tb < 4; ++tb) kfr[tb] = pack8(kc[0][tb] + b0, kc[1][tb] + b1);
    }
#pragma unroll
    for (int db = 0; db < 2; ++db) {
      float vbv = kvb[384 + h * 32 + db * 16 + m16];
      f32x4 bv = {vbv, vbv, vbv, vbv};
#pragma unroll
      for (int t = 0; t < 2; ++t)
        vfr[t][db] = pack8(vc[2 * t][db] + bv, vc[2 * t + 1][db] + bv);
    }

    // ---- attention per q-tile: S (1 MFMA/k-tile), softmax, PV ----
#pragma unroll
    for (int qt = 0; qt < 4; ++qt) {
      int q = qt * 16 + m16; int qcl = q < 49 ? q : 48;
      const float* bq = biasq + (size_t)(h * NTOK + qcl) * BIAS_RL;
      f32x4 s[4];
#pragma unroll
      for (int tb = 0; tb < 4; ++tb) s[tb] = MFMA16(kfr[tb], qfr[hh][qt], zf);

      float sv[4][4];
      float mx = -3.0e38f;
#pragma unroll
      for (int tb = 0; tb < 4; ++tb) {
        int k0 = tb * 16 + g * 4;
        int kcl = k0 <= 48 ? k0 : 48;     // bias row padded to 52, offset 48 is safe
        float4 bv = *(const float4*)(bq + kcl);
        sv[tb][0] = (k0 + 0 < 49) ? s[tb][0] + bv.x : -3.0e38f;
        sv[tb][1] = (k0 + 1 < 49) ? s[tb][1] + bv.y : -3.0e38f;
        sv[tb][2] = (k0 + 2 < 49) ? s[tb][2] + bv.z : -3.0e38f;
        sv[tb][3] = (k0 + 3 < 49) ? s[tb][3] + bv.w : -3.0e38f;
        mx = fmaxf(mx, fmaxf(fmaxf(sv[tb][0], sv[tb][1]), fmaxf(sv[tb][2], sv[tb][3])));
      }
      mx = fmaxf(mx, __shfl_xor(mx, 16));
      mx = fmaxf(mx, __shfl_xor(mx, 32));
      float sum = 0.f;
#pragma unroll
      for (int tb = 0; tb < 4; ++tb)
#pragma unroll
        for (int i = 0; i < 4; ++i) {
          float e = __expf(sv[tb][i] - mx);
          sv[tb][i] = e;
          sum += e;
        }
      sum += __shfl_xor(sum, 16);
      sum += __shfl_xor(sum, 32);
      float inv = 1.0f / sum;

      bf16x8 pfr[2];
#pragma unroll
      for (int t = 0; t < 2; ++t) {
        f32x4 lo = {sv[2 * t][0] * inv, sv[2 * t][1] * inv, sv[2 * t][2] * inv, sv[2 * t][3] * inv};
        f32x4 hi = {sv[2 * t + 1][0] * inv, sv[2 * t + 1][1] * inv, sv[2 * t + 1][2] * inv, sv[2 * t + 1][3] * inv};
        pfr[t] = pack8(lo, hi);
      }
      f32x4 o0 = zf, o1 = zf;
      o0 = MFMA16(pfr[0], vfr[0][0], o0); o0 = MFMA16(pfr[1], vfr[1][0], o0);
      o1 = MFMA16(pfr[0], vfr[0][1], o1); o1 = MFMA16(pfr[1], vfr[1][1], o1);
#pragma unroll
      for (int i = 0; i < 4; ++i) {
        int r = qt * 16 + g * 4 + i;
        if (r < 49) {
          OALL[r * 392 + h * 32 + m16]      = f2bf(o0[i]);
          OALL[r * 392 + h * 32 + 16 + m16] = f2bf(o1[i]);
        }
      }
    }
  }
  __syncthreads();   // [#3] OALL complete

  // ================= out-projection: wave owns col-tiles u*4..u*4+3 ========
  f32x4 pacc[4][4];
#pragma unroll
  for (int qt = 0; qt < 4; ++qt)
#pragma unroll
    for (int ct = 0; ct < 4; ++ct) pacc[qt][ct] = zf;
#pragma unroll
  for (int kk = 0; kk < 12; ++kk) {
    const int ko = kk * 32 + g * 8;
    bf16x8 af[4];
#pragma unroll
    for (int qt = 0; qt < 4; ++qt) {
      int r = qt * 16 + m16; r = r < 49 ? r : 48;
      af[qt] = *(const bf16x8*)(&OALL[r * 392 + ko]);
    }
#pragma unroll
    for (int ct = 0; ct < 4; ++ct) {
      bf16x8 bw = *(const bf16x8*)(wpT + (size_t)((u * 4 + ct) * 16 + m16) * 384 + ko);
#pragma unroll
      for (int qt = 0; qt < 4; ++qt) pacc[qt][ct] = MFMA16(af[qt], bw, pacc[qt][ct]);
    }
  }
  float* outw = out + (size_t)b * (NTOK * DIM);
#pragma unroll
  for (int ct = 0; ct < 4; ++ct) {
    int col = (u * 4 + ct) * 16 + m16;
    float pbv = pb[col];
#pragma unroll
    for (int qt = 0; qt < 4; ++qt)
#pragma unroll
      for (int i = 0; i < 4; ++i) {
        int r = qt * 16 + g * 4 + i;
        if (r < 49) outw[r * DIM + col] = pacc[qt][ct][i] + pbv;
      }
  }
}

extern "C" void kernel_launch(void* const* d_in, const int* in_sizes, int n_in,
                              void* d_out, int out_size, void* d_ws, size_t ws_size,
                              hipStream_t stream) {
  const float* xe  = (const float*)d_in[0];
  const float* xb  = (const float*)d_in[1];
  const float* qw  = (const float*)d_in[2];
  const float* qb  = (const float*)d_in[3];
  const float* kvw = (const float*)d_in[4];
  const float* kvb = (const float*)d_in[5];
  const float* pw  = (const float*)d_in[6];
  const float* pb  = (const float*)d_in[7];
  const float* bt  = (const float*)d_in[8];
  float* out = (float*)d_out;
  short* wsS = (short*)d_ws;
  float* biasq = (float*)((char*)d_ws + BIAS_BYTE_OFF);

  const int nwin = in_sizes[0] / (NTOK * DIM);

  const int prep_items = 384 * 384 + 768 * 384 + 384 * 384 + HEADS * NTOK * BIAS_RL;
  prep_kernel<<<(prep_items + 255) / 256, 256, 0, stream>>>(qw, kvw, pw, bt, wsS, biasq);

  hipFuncSetAttribute((const void*)fused_kernel,
                      hipFuncAttributeMaxDynamicSharedMemorySize, LDS_BYTES);
  fused_kernel<<<nwin, 384, LDS_BYTES, stream>>>(
      xe, xb, qb, kvb, pb,
      wsS + WQT_OFF, wsS + WKVT_OFF, wsS + WPT_OFF, biasq, out);
}